// Round 1
// baseline (1135.172 us; speedup 1.0000x reference)
//
#include <hip/hip_runtime.h>

typedef unsigned short u16;
typedef __attribute__((ext_vector_type(8))) short bf16x8;   // 8 bf16 in 4 VGPRs
typedef __attribute__((ext_vector_type(4))) float f32x4;

#define DEVI __device__ __forceinline__

// ---- problem constants (fixed by the reference) ----
static constexpr int TT  = 1024;   // tokens = B*S
static constexpr int HH  = 2048;   // hidden
static constexpr int II  = 1408;   // intermediate
static constexpr int FF  = 8;      // expert groups
static constexpr int ISH = 2816;   // shared intermediate

DEVI u16 f2bf(float f) {           // RNE float->bf16
  unsigned u = __float_as_uint(f);
  u += 0x7FFFu + ((u >> 16) & 1u);
  return (u16)(u >> 16);
}
DEVI float bf2f(u16 h) { return __uint_as_float((unsigned)h << 16); }
DEVI float silu(float x) { return x / (1.f + __expf(-x)); }

DEVI void gload16(const void* g, void* lds) {
  __builtin_amdgcn_global_load_lds(
      (const __attribute__((address_space(1))) unsigned int*)g,
      (__attribute__((address_space(3))) unsigned int*)lds, 16, 0, 0);
}

// ======================= GEMM =======================
// C(M x N) = A(M x Kd) * B^T, B stored (N x Kd) row-major (both bf16), fp32 out.
// B rows n < N1 come from B1; rows [N1, N1+N2) from B2 (concat trick: the LoRA
// qa matmul rides along as extra N-columns of the main GEMM -> C2).
// EPI==0: C1 = acc (raw).  EPI==1: C1 += scale[n] * acc.
// Batched over blockIdx.z with element strides s*.
template <int EPI>
__global__ __launch_bounds__(256) void k_gemm(
    const u16* __restrict__ A, const u16* __restrict__ B1,
    const u16* __restrict__ B2, float* __restrict__ C1, float* __restrict__ C2,
    const float* __restrict__ scale, int N1, int N2, int Kd, long sA, long sB1,
    long sB2, long sC1, long sC2, long sSc) {
  __shared__ u16 As[128 * 32];
  __shared__ u16 Bs[128 * 32];

  const int f = blockIdx.z;
  A += (long)f * sA;
  B1 += (long)f * sB1;
  if (B2) B2 += (long)f * sB2;
  C1 += (long)f * sC1;
  if (C2) C2 += (long)f * sC2;
  if (scale) scale += (long)f * sSc;

  const int tid = threadIdx.x;
  const int mBase = blockIdx.y * 128;
  const int nBase = blockIdx.x * 128;

  // staging: 512 chunks of 16B (=8 bf16); chunk c -> row c>>2, k-col (c&3)*8
  const int c0 = tid, c1 = tid + 256;
  const int kc0 = (c0 & 3) * 8, kc1 = (c1 & 3) * 8;
  const u16* aS0 = A + (long)(mBase + (c0 >> 2)) * Kd + kc0;
  const u16* aS1 = A + (long)(mBase + (c1 >> 2)) * Kd + kc1;
  const int nr0 = nBase + (c0 >> 2), nr1 = nBase + (c1 >> 2);
  const u16* bS0;
  const u16* bS1;
  if (nr0 < N1) bS0 = B1 + (long)nr0 * Kd;
  else { int r2 = nr0 - N1; if (r2 > N2 - 1) r2 = N2 - 1; bS0 = B2 + (long)r2 * Kd; }
  if (nr1 < N1) bS1 = B1 + (long)nr1 * Kd;
  else { int r2 = nr1 - N1; if (r2 > N2 - 1) r2 = N2 - 1; bS1 = B2 + (long)r2 * Kd; }
  bS0 += kc0;
  bS1 += kc1;

  const int l = tid & 63;
  const int w = tid >> 6;
  const int wr = (w >> 1) * 64;   // wave's 64x64 quadrant
  const int wc = (w & 1) * 64;
  const int lr = l & 15;
  const int lk = (l >> 4) * 8;    // contiguous 8-elem k chunk per 16-lane group

  f32x4 acc[4][4];
#pragma unroll
  for (int m = 0; m < 4; m++)
#pragma unroll
    for (int n = 0; n < 4; n++) acc[m][n] = (f32x4){0.f, 0.f, 0.f, 0.f};

  for (int k0 = 0; k0 < Kd; k0 += 32) {
    __syncthreads();                 // prev ds_reads done before overwrite
    gload16(aS0 + k0, &As[c0 * 8]);
    gload16(aS1 + k0, &As[c1 * 8]);
    gload16(bS0 + k0, &Bs[c0 * 8]);
    gload16(bS1 + k0, &Bs[c1 * 8]);
    __syncthreads();                 // compiler drains vmcnt before s_barrier
    bf16x8 av[4], bv[4];
#pragma unroll
    for (int m = 0; m < 4; m++)
      av[m] = *(const bf16x8*)&As[(wr + m * 16 + lr) * 32 + lk];
#pragma unroll
    for (int n = 0; n < 4; n++)
      bv[n] = *(const bf16x8*)&Bs[(wc + n * 16 + lr) * 32 + lk];
#pragma unroll
    for (int m = 0; m < 4; m++)
#pragma unroll
      for (int n = 0; n < 4; n++)
        acc[m][n] = __builtin_amdgcn_mfma_f32_16x16x32_bf16(av[m], bv[n],
                                                            acc[m][n], 0, 0, 0);
  }

  // C/D layout (m89-verified): col = lane&15, row = (lane>>4)*4 + reg
  const int colB = nBase + wc + lr;
  const int rowB = mBase + wr + (l >> 4) * 4;
#pragma unroll
  for (int m = 0; m < 4; m++) {
#pragma unroll
    for (int n = 0; n < 4; n++) {
      const int col = colB + n * 16;
      f32x4 v = acc[m][n];
#pragma unroll
      for (int j = 0; j < 4; j++) {
        const int row = rowB + m * 16 + j;
        if (col < N1) {
          float* p = C1 + (long)row * N1 + col;
          if (EPI == 1) *p += scale[col] * v[j];
          else *p = v[j];
        } else if (col < N1 + N2) {
          C2[(long)row * N2 + (col - N1)] = v[j];
        }
      }
    }
  }
}

// ======================= gating (pure fp32 to match reference top-k) ==========
__global__ __launch_bounds__(64) void k_gate(const float* __restrict__ x,
                                             const float* __restrict__ gw,
                                             const int* __restrict__ inv,
                                             float* __restrict__ soft,
                                             float* __restrict__ scalar) {
  const int t = blockIdx.x;
  const int e = threadIdx.x;  // one wave, lane = expert
  __shared__ float4 xs[512];
  const float4* xr = (const float4*)(x + (long)t * HH);
#pragma unroll
  for (int i = 0; i < 8; i++) xs[e + i * 64] = xr[e + i * 64];
  __syncthreads();
  const float4* g = (const float4*)(gw + (long)e * HH);
  float s = 0.f;
#pragma unroll 4
  for (int i = 0; i < 512; i++) {
    float4 gv = g[i];
    float4 xv = xs[i];
    s += gv.x * xv.x + gv.y * xv.y + gv.z * xv.z + gv.w * xv.w;
  }
  // softmax over 64 experts
  float mx = s;
#pragma unroll
  for (int d = 1; d < 64; d <<= 1) mx = fmaxf(mx, __shfl_xor(mx, d));
  float pe = __expf(s - mx);
  float sm = pe;
#pragma unroll
  for (int d = 1; d < 64; d <<= 1) sm += __shfl_xor(sm, d);
  float prob = pe / sm;
  // top-6 (ties -> lowest index, like jax top_k)
  float wd = 0.f;
  bool sel = false;
  for (int it = 0; it < 6; it++) {
    float cand = sel ? -1.f : prob;
    float cmx = cand;
#pragma unroll
    for (int d = 1; d < 64; d <<= 1) cmx = fmaxf(cmx, __shfl_xor(cmx, d));
    unsigned long long b = __ballot(cand == cmx);
    int win = __ffsll((long long)b) - 1;
    if (e == win) { sel = true; wd = prob; }
  }
  // flat = w_dense[:, inv_mapping]; group-of-8 sum + masked softmax
  int src = inv[e];
  float flat = __shfl(wd, src);
  float sum8 = flat;
#pragma unroll
  for (int d = 1; d < 8; d <<= 1) sum8 += __shfl_xor(sum8, d);
  float masked = (flat == 0.f) ? -1e9f : flat;
  float m8 = masked;
#pragma unroll
  for (int d = 1; d < 8; d <<= 1) m8 = fmaxf(m8, __shfl_xor(m8, d));
  float p = __expf(masked - m8);
  float ps = p;
#pragma unroll
  for (int d = 1; d < 8; d <<= 1) ps += __shfl_xor(ps, d);
  soft[(long)t * 64 + e] = p / ps;
  if ((e & 7) == 0) scalar[(long)t * 8 + (e >> 3)] = sum8;
}

// ======================= small fused / conversion kernels =====================
__global__ void k_cvt(const float* __restrict__ s, u16* __restrict__ d, long n4) {
  long i = (long)blockIdx.x * blockDim.x + threadIdx.x;
  long st = (long)gridDim.x * blockDim.x;
  for (; i < n4; i += st) {
    float4 v = ((const float4*)s)[i];
    ushort4 o;
    o.x = f2bf(v.x); o.y = f2bf(v.y); o.z = f2bf(v.z); o.w = f2bf(v.w);
    ((ushort4*)d)[i] = o;
  }
}

// qb (F,8,N,8) fp32 -> QB (F,N,64) bf16 with QB[f,i,k*8+r] = qb[f,k,i,r]
__global__ void k_qbt(const float* __restrict__ qb, u16* __restrict__ QB, int N,
                      long n) {
  long i = (long)blockIdx.x * blockDim.x + threadIdx.x;
  long st = (long)gridDim.x * blockDim.x;
  for (; i < n; i += st) {
    int kr = (int)(i & 63);
    long fi = i >> 6;
    int ii = (int)(fi % N);
    int f = (int)(fi / N);
    int k = kr >> 3, r = kr & 7;
    QB[i] = f2bf(qb[(((long)(f * 8 + k) * N + ii) << 3) + r]);
  }
}

// XE[f,t,h] = x[t,h] + sum_k soft[t,f,k]*muW[f,h,k]   (bf16 out)
__global__ void k_xe(const float* __restrict__ x, const float* __restrict__ muW,
                     const float* __restrict__ soft, u16* __restrict__ XE) {
  const int t = blockIdx.x, f = blockIdx.y, tid = threadIdx.x;
  float w[8];
#pragma unroll
  for (int k = 0; k < 8; k++) w[k] = soft[(long)t * 64 + f * 8 + k];
  const long xo = (long)t * HH;
  const long eo = ((long)f * TT + t) * HH;
#pragma unroll
  for (int i = 0; i < 8; i++) {
    int h = tid + i * 256;
    const float4* mu = (const float4*)(muW + ((long)f * HH + h) * 8);
    float4 m0 = mu[0], m1 = mu[1];
    float v = x[xo + h];
    v += w[0] * m0.x + w[1] * m0.y + w[2] * m0.z + w[3] * m0.w +
         w[4] * m1.x + w[5] * m1.y + w[6] * m1.z + w[7] * m1.w;
    XE[eo + h] = f2bf(v);
  }
}

// Cg/Cu[f,t,kr] = bf16(A*[f,t,kr] * soft[t,f,kr>>3])
__global__ void k_cw(const float* __restrict__ Ag, const float* __restrict__ Au,
                     const float* __restrict__ soft, u16* __restrict__ Cg,
                     u16* __restrict__ Cu) {
  const long n = (long)FF * TT * 64;
  long i = (long)blockIdx.x * blockDim.x + threadIdx.x;
  long st = (long)gridDim.x * blockDim.x;
  for (; i < n; i += st) {
    int kr = (int)(i & 63);
    int t = (int)((i >> 6) & 1023);
    int f = (int)(i >> 16);
    float w = soft[(long)t * 64 + f * 8 + (kr >> 3)];
    Cg[i] = f2bf(Ag[i] * w);
    Cu[i] = f2bf(Au[i] * w);
  }
}

__global__ void k_cd(const float* __restrict__ Ad, const float* __restrict__ soft,
                     u16* __restrict__ Cd) {
  const long n = (long)FF * TT * 64;
  long i = (long)blockIdx.x * blockDim.x + threadIdx.x;
  long st = (long)gridDim.x * blockDim.x;
  for (; i < n; i += st) {
    int kr = (int)(i & 63);
    int t = (int)((i >> 6) & 1023);
    int f = (int)(i >> 16);
    Cd[i] = f2bf(Ad[i] * soft[(long)t * 64 + f * 8 + (kr >> 3)]);
  }
}

// Hb = bf16( silu(G_lin) * U_lin )
__global__ void k_h(const float* __restrict__ G, const float* __restrict__ U,
                    u16* __restrict__ Hb) {
  const long n = (long)FF * TT * II;
  long i = (long)blockIdx.x * blockDim.x + threadIdx.x;
  long st = (long)gridDim.x * blockDim.x;
  for (; i < n; i += st) Hb[i] = f2bf(silu(G[i]) * U[i]);
}

__global__ void k_hsh(const float* __restrict__ G, const float* __restrict__ U,
                      u16* __restrict__ Hb) {
  const long n = (long)TT * ISH;
  long i = (long)blockIdx.x * blockDim.x + threadIdx.x;
  long st = (long)gridDim.x * blockDim.x;
  for (; i < n; i += st) Hb[i] = f2bf(silu(G[i]) * U[i]);
}

// out[t,h] = Ysh[t,h] + sum_f scalar[t,f] * Yp[f,t,h]
__global__ void k_final(const float* __restrict__ Yp, const float* __restrict__ Ysh,
                        const float* __restrict__ scalar, float* __restrict__ out) {
  const long n = (long)TT * HH;
  long i = (long)blockIdx.x * blockDim.x + threadIdx.x;
  long st = (long)gridDim.x * blockDim.x;
  for (; i < n; i += st) {
    int t = (int)(i >> 11);
    float a = Ysh[i];
#pragma unroll
    for (int f = 0; f < FF; f++) a += scalar[t * 8 + f] * Yp[(long)f * n + i];
    out[i] = a;
  }
}

// ======================= launch =======================
extern "C" void kernel_launch(void* const* d_in, const int* in_sizes, int n_in,
                              void* d_out, int out_size, void* d_ws,
                              size_t ws_size, hipStream_t stream) {
  const float* xf   = (const float*)d_in[0];
  const float* gwf  = (const float*)d_in[1];
  const int*   invp = (const int*)d_in[2];
  const float* muWf = (const float*)d_in[3];
  const float* gW   = (const float*)d_in[4];
  const float* gqa  = (const float*)d_in[5];
  const float* gqb  = (const float*)d_in[6];
  const float* gscf = (const float*)d_in[7];
  const float* uW   = (const float*)d_in[8];
  const float* uqa  = (const float*)d_in[9];
  const float* uqb  = (const float*)d_in[10];
  const float* uscf = (const float*)d_in[11];
  const float* dW   = (const float*)d_in[12];
  const float* dqa  = (const float*)d_in[13];
  const float* dqb  = (const float*)d_in[14];
  const float* dscf = (const float*)d_in[15];
  const float* shgW = (const float*)d_in[16];
  const float* shuW = (const float*)d_in[17];
  const float* shdW = (const float*)d_in[18];
  float* outp = (float*)d_out;

  // ---- workspace layout (total ~330 MiB); later buffers alias dead earlier ones
  constexpr long SZ_WG  = (long)FF * II * HH * 2;   // 46,137,344
  constexpr long SZ_SH  = (long)ISH * HH * 2;       // 11,534,336
  constexpr long SZ_QAH = (long)FF * 64 * HH * 2;
  constexpr long SZ_QAI = (long)FF * 64 * II * 2;
  constexpr long SZ_QBI = (long)FF * II * 64 * 2;
  constexpr long SZ_QBH = (long)FF * HH * 64 * 2;
  constexpr long SZ_XB  = (long)TT * HH * 2;
  constexpr long SZ_SOFT = (long)TT * 64 * 4;
  constexpr long SZ_SCAL = (long)TT * 8 * 4;
  constexpr long SZ_XE  = (long)FF * TT * HH * 2;   // 33,554,432
  constexpr long SZ_A   = (long)FF * TT * 64 * 4;
  constexpr long SZ_C   = (long)FF * TT * 64 * 2;
  constexpr long SZ_G   = (long)FF * TT * II * 4;   // 46,137,344
  constexpr long SZ_HB  = (long)FF * TT * II * 2;

  char* base = (char*)d_ws;
  size_t off = 0;
  auto take = [&](long sz) { char* r = base + off; off += (size_t)sz; return r; };
  u16* Wg  = (u16*)take(SZ_WG);
  u16* Wu  = (u16*)take(SZ_WG);
  u16* Wd  = (u16*)take(SZ_WG);
  u16* SHg = (u16*)take(SZ_SH);
  u16* SHu = (u16*)take(SZ_SH);
  u16* SHd = (u16*)take(SZ_SH);
  u16* QAg = (u16*)take(SZ_QAH);
  u16* QAu = (u16*)take(SZ_QAH);
  u16* QAd = (u16*)take(SZ_QAI);
  u16* QBg = (u16*)take(SZ_QBI);
  u16* QBu = (u16*)take(SZ_QBI);
  u16* QBd = (u16*)take(SZ_QBH);
  u16* Xb  = (u16*)take(SZ_XB);
  float* Soft = (float*)take(SZ_SOFT);
  float* Scal = (float*)take(SZ_SCAL);
  char* xeR = take(SZ_XE);            // XE; later Gs/Us/Hsh (shared path)
  u16* Xe = (u16*)xeR;
  float* Gs = (float*)xeR;                       // 1024*2816*4 = 11,534,336
  float* Us = (float*)(xeR + 11534336);
  u16* Hsh  = (u16*)(xeR + 23068672);            // needs 5,767,168 (fits)
  char* aR = take(3 * SZ_A + 3 * SZ_C);          // Ag,Au,Ad,Cg,Cu,Cd; later Ysh
  float* Ag = (float*)aR;
  float* Au = (float*)(aR + SZ_A);
  float* Ad = (float*)(aR + 2 * SZ_A);
  u16* Cg = (u16*)(aR + 3 * SZ_A);
  u16* Cu = (u16*)(aR + 3 * SZ_A + SZ_C);
  u16* Cd = (u16*)(aR + 3 * SZ_A + 2 * SZ_C);
  float* Ysh = (float*)aR;                       // 8,388,608 <= 9,437,184
  char* gR = take(2 * SZ_G);                     // G,U; later Ypart
  float* Gb = (float*)gR;
  float* Ub = (float*)(gR + SZ_G);
  float* Yp = (float*)gR;                        // 67,108,864 <= 92,274,688
  u16* Hb = (u16*)take(SZ_HB);
  if (ws_size < off) return;  // loud failure rather than OOB corruption

  auto cvt = [&](const float* s, u16* d, long n) {
    long n4 = n >> 2;
    int blocks = (int)((n4 + 255) / 256);
    if (blocks > 2048) blocks = 2048;
    k_cvt<<<blocks, 256, 0, stream>>>(s, d, n4);
  };
  auto qbt = [&](const float* s, u16* d, int N) {
    long n = (long)FF * N * 64;
    int blocks = (int)((n + 255) / 256);
    if (blocks > 1024) blocks = 1024;
    k_qbt<<<blocks, 256, 0, stream>>>(s, d, N, n);
  };
  auto gemm = [&](int epi, const u16* Aop, const u16* B1, const u16* B2,
                  float* C1, float* C2, const float* sc, int N1, int N2, int Kd,
                  long sA, long sB1, long sB2, long sC1, long sC2, long sSc,
                  int zf) {
    dim3 grid((unsigned)((N1 + N2 + 127) / 128), TT / 128, (unsigned)zf);
    if (epi == 0)
      k_gemm<0><<<grid, 256, 0, stream>>>(Aop, B1, B2, C1, C2, sc, N1, N2, Kd,
                                          sA, sB1, sB2, sC1, sC2, sSc);
    else
      k_gemm<1><<<grid, 256, 0, stream>>>(Aop, B1, B2, C1, C2, sc, N1, N2, Kd,
                                          sA, sB1, sB2, sC1, sC2, sSc);
  };

  // 1) fp32 -> bf16 weight/activation conversions
  cvt(xf, Xb, (long)TT * HH);
  cvt(gW, Wg, (long)FF * II * HH);
  cvt(uW, Wu, (long)FF * II * HH);
  cvt(dW, Wd, (long)FF * HH * II);
  cvt(shgW, SHg, (long)ISH * HH);
  cvt(shuW, SHu, (long)ISH * HH);
  cvt(shdW, SHd, (long)HH * ISH);
  cvt(gqa, QAg, (long)FF * 64 * HH);
  cvt(uqa, QAu, (long)FF * 64 * HH);
  cvt(dqa, QAd, (long)FF * 64 * II);
  qbt(gqb, QBg, II);
  qbt(uqb, QBu, II);
  qbt(dqb, QBd, HH);

  // 2) gating (fp32, exact top-k semantics) + per-expert input
  k_gate<<<TT, 64, 0, stream>>>(xf, gwf, invp, Soft, Scal);
  k_xe<<<dim3(TT, FF), 256, 0, stream>>>(xf, muWf, Soft, Xe);

  // 3) expert path, batched over f (blockIdx.z). qa rides as extra N-cols.
  gemm(0, Xe, Wg, QAg, Gb, Ag, nullptr, II, 64, HH, (long)TT * HH,
       (long)II * HH, 64L * HH, (long)TT * II, (long)TT * 64, 0, FF);
  gemm(0, Xe, Wu, QAu, Ub, Au, nullptr, II, 64, HH, (long)TT * HH,
       (long)II * HH, 64L * HH, (long)TT * II, (long)TT * 64, 0, FF);
  k_cw<<<512, 256, 0, stream>>>(Ag, Au, Soft, Cg, Cu);
  gemm(1, Cg, QBg, nullptr, Gb, nullptr, gscf, II, 0, 64, (long)TT * 64,
       (long)II * 64, 0, (long)TT * II, 0, II, FF);
  gemm(1, Cu, QBu, nullptr, Ub, nullptr, uscf, II, 0, 64, (long)TT * 64,
       (long)II * 64, 0, (long)TT * II, 0, II, FF);
  k_h<<<2048, 256, 0, stream>>>(Gb, Ub, Hb);
  gemm(0, Hb, Wd, QAd, Yp, Ad, nullptr, HH, 64, II, (long)TT * II,
       (long)HH * II, 64L * II, (long)TT * HH, (long)TT * 64, 0, FF);
  k_cd<<<512, 256, 0, stream>>>(Ad, Soft, Cd);
  gemm(1, Cd, QBd, nullptr, Yp, nullptr, dscf, HH, 0, 64, (long)TT * 64,
       (long)HH * 64, 0, (long)TT * HH, 0, HH, FF);

  // 4) shared expert (runs last: its buffers alias XE / A-C regions)
  gemm(0, Xb, SHg, nullptr, Gs, nullptr, nullptr, ISH, 0, HH, 0, 0, 0, 0, 0, 0, 1);
  gemm(0, Xb, SHu, nullptr, Us, nullptr, nullptr, ISH, 0, HH, 0, 0, 0, 0, 0, 0, 1);
  k_hsh<<<512, 256, 0, stream>>>(Gs, Us, Hsh);
  gemm(0, Hsh, SHd, nullptr, Ysh, nullptr, nullptr, HH, 0, ISH, 0, 0, 0, 0, 0, 0, 1);

  // 5) weighted combine
  k_final<<<1024, 256, 0, stream>>>(Yp, Ysh, Scal, outp);
}

// Round 2
// 915.861 us; speedup vs baseline: 1.2395x; 1.2395x over previous
//
#include <hip/hip_runtime.h>

typedef unsigned short u16;
typedef __attribute__((ext_vector_type(8))) short bf16x8;   // 8 bf16 in 4 VGPRs
typedef __attribute__((ext_vector_type(4))) float f32x4;

#define DEVI __device__ __forceinline__

// ---- problem constants ----
static constexpr int TT = 1024, HH = 2048, II = 1408, FF = 8, ISHc = 2816;
static constexpr int NCAT = 2944;  // 1408 gate | 64 gate_qa | 1408 up | 64 up_qa
static constexpr int NDC  = 2112;  // 2048 down | 64 down_qa

DEVI u16 f2bf(float f) {  // RNE float->bf16
  unsigned u = __float_as_uint(f);
  u += 0x7FFFu + ((u >> 16) & 1u);
  return (u16)(u >> 16);
}
DEVI float silu(float x) { return x / (1.f + __expf(-x)); }
DEVI void gload16(const void* g, void* lds) {
  __builtin_amdgcn_global_load_lds(
      (const __attribute__((address_space(1))) unsigned*)g,
      (__attribute__((address_space(3))) unsigned*)lds, 16, 0, 0);
}
// m204 bijective XCD-chunk swizzle (nwg % 8 == 0 for all our grids):
// hw assigns XCD = blockIdx % 8; remap so each XCD owns a contiguous tile range.
DEVI int xswz(int o, int nwg) { return (o & 7) * (nwg >> 3) + (o >> 3); }

// ======================= GEMM core (128x128, BK=32, proven round-1) ==========
// C(MxN tile) = A(row-major, stride Kd) * B^T (B rows n, stride Kd), fp32 out.
// EPI==0: C = acc.  EPI==1: C += scale[col] * acc.
template <int EPI>
DEVI void gemm_core(const u16* __restrict__ A, const u16* __restrict__ B,
                    float* __restrict__ C, const float* __restrict__ scale,
                    int N, int Kd, int ldC, int mBase, int nBase) {
  __shared__ u16 As[128 * 32];
  __shared__ u16 Bs[128 * 32];
  const int tid = threadIdx.x;
  const int c0 = tid, c1 = tid + 256;
  const int kc0 = (c0 & 3) * 8, kc1 = (c1 & 3) * 8;
  const u16* aS0 = A + (long)(mBase + (c0 >> 2)) * Kd + kc0;
  const u16* aS1 = A + (long)(mBase + (c1 >> 2)) * Kd + kc1;
  int nr0 = nBase + (c0 >> 2); if (nr0 > N - 1) nr0 = N - 1;  // edge clamp
  int nr1 = nBase + (c1 >> 2); if (nr1 > N - 1) nr1 = N - 1;
  const u16* bS0 = B + (long)nr0 * Kd + kc0;
  const u16* bS1 = B + (long)nr1 * Kd + kc1;

  const int l = tid & 63, w = tid >> 6;
  const int wr = (w >> 1) * 64, wc = (w & 1) * 64;  // wave's 64x64 quadrant
  const int lr = l & 15, lk = (l >> 4) * 8;

  f32x4 acc[4][4];
#pragma unroll
  for (int m = 0; m < 4; m++)
#pragma unroll
    for (int n = 0; n < 4; n++) acc[m][n] = (f32x4){0.f, 0.f, 0.f, 0.f};

  for (int k0 = 0; k0 < Kd; k0 += 32) {
    __syncthreads();  // prev ds_reads done before overwrite
    gload16(aS0 + k0, &As[c0 * 8]);
    gload16(aS1 + k0, &As[c1 * 8]);
    gload16(bS0 + k0, &Bs[c0 * 8]);
    gload16(bS1 + k0, &Bs[c1 * 8]);
    __syncthreads();  // compiler drains vmcnt before s_barrier
    bf16x8 av[4], bv[4];
#pragma unroll
    for (int m = 0; m < 4; m++)
      av[m] = *(const bf16x8*)&As[(wr + m * 16 + lr) * 32 + lk];
#pragma unroll
    for (int n = 0; n < 4; n++)
      bv[n] = *(const bf16x8*)&Bs[(wc + n * 16 + lr) * 32 + lk];
#pragma unroll
    for (int m = 0; m < 4; m++)
#pragma unroll
      for (int n = 0; n < 4; n++)
        acc[m][n] = __builtin_amdgcn_mfma_f32_16x16x32_bf16(av[m], bv[n],
                                                            acc[m][n], 0, 0, 0);
  }

  // C/D layout (m89-verified): col = lane&15, row = (lane>>4)*4 + reg
  const int colB = nBase + wc + lr;
  const int rowB = mBase + wr + (l >> 4) * 4;
#pragma unroll
  for (int m = 0; m < 4; m++)
#pragma unroll
    for (int n = 0; n < 4; n++) {
      const int col = colB + n * 16;
      if (col < N) {
        const float sc = (EPI == 1) ? scale[col] : 0.f;
        f32x4 v = acc[m][n];
        float* p = C + (long)(rowB + m * 16) * ldC + col;
#pragma unroll
        for (int j = 0; j < 4; j++) {
          if (EPI == 1) p[(long)j * ldC] += sc * v[j];
          else p[(long)j * ldC] = v[j];
        }
      }
    }
}

// ======================= GEMM wrappers (swizzled decode) =====================
// G1: z=0..7 expert gate|qa|up|qa (A=Xe[f]); z=8,9 shared gate/up (A=Xb).
// N=2944=23x128 tiles, M=8 tiles -> 184 tiles/z, 1840 blocks.
__global__ __launch_bounds__(256) void k_g1(const u16* __restrict__ Xe,
                                            const u16* __restrict__ Xb,
                                            const u16* __restrict__ Wcat,
                                            float* __restrict__ Cat) {
  int wg = xswz(blockIdx.x, 1840);
  int z = wg / 184, rr = wg % 184;
  int nB = (rr % 23) * 128, mB = (rr / 23) * 128;
  const u16* A = (z < 8) ? Xe + (long)z * TT * HH : Xb;
  gemm_core<0>(A, Wcat + (long)z * NCAT * HH, Cat + (long)z * TT * NCAT,
               nullptr, NCAT, HH, NCAT, mB, nB);
}

// G2: per-XCD chunk = 17 shared-down tiles (K=2816) + 136 expert tiles (f=xcd,
// K=1408) for uniform per-XCD work. 1224 blocks.
__global__ __launch_bounds__(256) void k_g2(const u16* __restrict__ Hb,
                                            const u16* __restrict__ Hsh,
                                            const u16* __restrict__ Wd,
                                            const u16* __restrict__ SHd,
                                            float* __restrict__ Dcat) {
  int wg = xswz(blockIdx.x, 1224);
  int xcd = wg / 153, j = wg % 153;
  if (j < 17) {  // shared-down: N=2048 (16 tiles), tile 16 exits
    int s = xcd * 17 + j;
    int nB = (s % 17) * 128, mB = (s / 17) * 128;
    if (nB >= HH) return;
    gemm_core<0>(Hsh, SHd, Dcat + 8L * TT * NDC, nullptr, HH, ISHc, NDC, mB, nB);
  } else {       // expert down: N=2112 (17 tiles, last clamped)
    int e = j - 17, f = xcd;
    int nB = (e % 17) * 128, mB = (e / 17) * 128;
    gemm_core<0>(Hb + (long)f * TT * II, Wd + (long)f * NDC * II,
                 Dcat + (long)f * TT * NDC, nullptr, NDC, II, NDC, mB, nB);
  }
}

// M1: gate-mix (z<8) and up-mix (z>=8), K=64, += scale into Cat. 1408 blocks.
__global__ __launch_bounds__(256) void k_m1(const u16* __restrict__ Cg,
                                            const u16* __restrict__ Cu,
                                            const u16* __restrict__ QBg,
                                            const u16* __restrict__ QBu,
                                            float* __restrict__ Cat,
                                            const float* __restrict__ gsc,
                                            const float* __restrict__ usc) {
  int wg = xswz(blockIdx.x, 1408);
  int z = wg / 88, rr = wg % 88;
  int nB = (rr % 11) * 128, mB = (rr / 11) * 128;
  int f = z & 7;
  bool gate = z < 8;
  const u16* A = (gate ? Cg : Cu) + (long)f * TT * 64;
  const u16* B = (gate ? QBg : QBu) + (long)f * II * 64;
  float* C = Cat + (long)f * TT * NCAT + (gate ? 0 : 1472);
  const float* sc = (gate ? gsc : usc) + (long)f * II;
  gemm_core<1>(A, B, C, sc, II, 64, NCAT, mB, nB);
}

// M2: down-mix, K=64, += dscale into Dcat. 1024 blocks.
__global__ __launch_bounds__(256) void k_m2(const u16* __restrict__ Cd,
                                            const u16* __restrict__ QBd,
                                            float* __restrict__ Dcat,
                                            const float* __restrict__ dsc) {
  int wg = xswz(blockIdx.x, 1024);
  int f = wg / 128, rr = wg % 128;
  int nB = (rr % 16) * 128, mB = (rr / 16) * 128;
  gemm_core<1>(Cd + (long)f * TT * 64, QBd + (long)f * HH * 64,
               Dcat + (long)f * TT * NDC, dsc + (long)f * HH, HH, 64, NDC, mB, nB);
}

// ======================= gating (fp32, exact top-k semantics) ================
__global__ __launch_bounds__(64) void k_gate(const float* __restrict__ x,
                                             const float* __restrict__ gw,
                                             const int* __restrict__ inv,
                                             float* __restrict__ soft,
                                             float* __restrict__ scalar) {
  const int t = blockIdx.x;
  const int e = threadIdx.x;  // one wave, lane = expert
  __shared__ float4 xs[512];
  const float4* xr = (const float4*)(x + (long)t * HH);
#pragma unroll
  for (int i = 0; i < 8; i++) xs[e + i * 64] = xr[e + i * 64];
  __syncthreads();
  const float4* g = (const float4*)(gw + (long)e * HH);
  float s = 0.f;
#pragma unroll 4
  for (int i = 0; i < 512; i++) {
    float4 gv = g[i];
    float4 xv = xs[i];
    s += gv.x * xv.x + gv.y * xv.y + gv.z * xv.z + gv.w * xv.w;
  }
  float mx = s;
#pragma unroll
  for (int d = 1; d < 64; d <<= 1) mx = fmaxf(mx, __shfl_xor(mx, d));
  float pe = __expf(s - mx);
  float sm = pe;
#pragma unroll
  for (int d = 1; d < 64; d <<= 1) sm += __shfl_xor(sm, d);
  float prob = pe / sm;
  float wd = 0.f;
  bool sel = false;
  for (int it = 0; it < 6; it++) {  // top-6, ties -> lowest index
    float cand = sel ? -1.f : prob;
    float cmx = cand;
#pragma unroll
    for (int d = 1; d < 64; d <<= 1) cmx = fmaxf(cmx, __shfl_xor(cmx, d));
    unsigned long long b = __ballot(cand == cmx);
    int win = __ffsll((long long)b) - 1;
    if (e == win) { sel = true; wd = prob; }
  }
  int src = inv[e];
  float flat = __shfl(wd, src);
  float sum8 = flat;
#pragma unroll
  for (int d = 1; d < 8; d <<= 1) sum8 += __shfl_xor(sum8, d);
  float masked = (flat == 0.f) ? -1e9f : flat;
  float m8 = masked;
#pragma unroll
  for (int d = 1; d < 8; d <<= 1) m8 = fmaxf(m8, __shfl_xor(m8, d));
  float p = __expf(masked - m8);
  float ps = p;
#pragma unroll
  for (int d = 1; d < 8; d <<= 1) ps += __shfl_xor(ps, d);
  soft[(long)t * 64 + e] = p / ps;
  if ((e & 7) == 0) scalar[(long)t * 8 + (e >> 3)] = sum8;
}

// ======================= conversion / glue kernels ===========================
// Wcat: 10 slices of (2944 x 2048) bf16; z<8: [gW | gqa | uW | uqa](f);
// z=8: sh_gate + zero pad; z=9: sh_up + zero pad.
__global__ void k_cvt_wcat(const float* __restrict__ gW,
                           const float* __restrict__ gqa,
                           const float* __restrict__ uW,
                           const float* __restrict__ uqa,
                           const float* __restrict__ shg,
                           const float* __restrict__ shu,
                           u16* __restrict__ Wcat) {
  const long tot = 10L * NCAT * (HH / 4);
  long i = (long)blockIdx.x * blockDim.x + threadIdx.x;
  long st = (long)gridDim.x * blockDim.x;
  for (; i < tot; i += st) {
    int h4 = (int)(i & 511);
    long rz = i >> 9;
    int row = (int)(rz % NCAT);
    int z = (int)(rz / NCAT);
    const float* src = nullptr;
    if (z < 8) {
      if (row < 1408)       src = gW  + ((long)z * II + row) * HH;
      else if (row < 1472)  src = gqa + ((long)z * 64 + row - 1408) * HH;
      else if (row < 2880)  src = uW  + ((long)z * II + row - 1472) * HH;
      else                  src = uqa + ((long)z * 64 + row - 2880) * HH;
    } else if (row < ISHc) {
      src = ((z == 8) ? shg : shu) + (long)row * HH;
    }
    ushort4 o;
    if (src) {
      float4 v = ((const float4*)src)[h4];
      o.x = f2bf(v.x); o.y = f2bf(v.y); o.z = f2bf(v.z); o.w = f2bf(v.w);
    } else { o.x = 0; o.y = 0; o.z = 0; o.w = 0; }
    ((ushort4*)Wcat)[i] = o;
  }
}

// Wdcat (8 x 2112 x 1408) = [dW | dqa](f);  SHdb (2048 x 2816) = sh_down.
__global__ void k_cvt_wd(const float* __restrict__ dW,
                         const float* __restrict__ dqa,
                         const float* __restrict__ shdW, u16* __restrict__ Wd,
                         u16* __restrict__ SHd) {
  const long s1 = 8L * NDC * (II / 4);
  const long s2 = s1 + (long)HH * (ISHc / 4);
  long i = (long)blockIdx.x * blockDim.x + threadIdx.x;
  long st = (long)gridDim.x * blockDim.x;
  for (; i < s2; i += st) {
    ushort4 o;
    if (i < s1) {
      int k4 = (int)(i % 352);
      long rz = i / 352;
      int row = (int)(rz % NDC);
      int f = (int)(rz / NDC);
      const float* src = (row < HH) ? dW + ((long)f * HH + row) * II
                                    : dqa + ((long)f * 64 + (row - HH)) * II;
      float4 v = ((const float4*)src)[k4];
      o.x = f2bf(v.x); o.y = f2bf(v.y); o.z = f2bf(v.z); o.w = f2bf(v.w);
      ((ushort4*)Wd)[i] = o;
    } else {
      long j = i - s1;
      float4 v = ((const float4*)shdW)[j];
      o.x = f2bf(v.x); o.y = f2bf(v.y); o.z = f2bf(v.z); o.w = f2bf(v.w);
      ((ushort4*)SHd)[j] = o;
    }
  }
}

__global__ void k_cvt_x(const float* __restrict__ x, u16* __restrict__ Xb) {
  const long n4 = (long)TT * HH / 4;
  long i = (long)blockIdx.x * blockDim.x + threadIdx.x;
  long st = (long)gridDim.x * blockDim.x;
  for (; i < n4; i += st) {
    float4 v = ((const float4*)x)[i];
    ushort4 o;
    o.x = f2bf(v.x); o.y = f2bf(v.y); o.z = f2bf(v.z); o.w = f2bf(v.w);
    ((ushort4*)Xb)[i] = o;
  }
}

// QB[f,i,kr] = qb[f, kr>>3, i, kr&7]  for gate/up (N=II) and down (N=HH)
__global__ void k_qbt3(const float* __restrict__ gqb,
                       const float* __restrict__ uqb,
                       const float* __restrict__ dqb, u16* __restrict__ QBg,
                       u16* __restrict__ QBu, u16* __restrict__ QBd) {
  const long n1 = 8L * II * 64, n2 = 2 * n1, n3 = n2 + 8L * HH * 64;
  long i = (long)blockIdx.x * blockDim.x + threadIdx.x;
  long st = (long)gridDim.x * blockDim.x;
  for (; i < n3; i += st) {
    const float* q; u16* d; int N; long j;
    if (i < n1)      { q = gqb; d = QBg; N = II; j = i; }
    else if (i < n2) { q = uqb; d = QBu; N = II; j = i - n1; }
    else             { q = dqb; d = QBd; N = HH; j = i - n2; }
    int kr = (int)(j & 63);
    long rest = j >> 6;
    int ii = (int)(rest % N);
    int f = (int)(rest / N);
    d[j] = f2bf(q[(((long)(f * 8 + (kr >> 3)) * N + ii) << 3) + (kr & 7)]);
  }
}

// XE[f,t,h] = x[t,h] + sum_k soft[t,f,k]*muW[f,h,k]
__global__ void k_xe(const float* __restrict__ x, const float* __restrict__ muW,
                     const float* __restrict__ soft, u16* __restrict__ XE) {
  const int t = blockIdx.x, f = blockIdx.y, tid = threadIdx.x;
  float w[8];
#pragma unroll
  for (int k = 0; k < 8; k++) w[k] = soft[(long)t * 64 + f * 8 + k];
  const long xo = (long)t * HH;
  const long eo = ((long)f * TT + t) * HH;
#pragma unroll
  for (int i = 0; i < 8; i++) {
    int h = tid + i * 256;
    const float4* mu = (const float4*)(muW + ((long)f * HH + h) * 8);
    float4 m0 = mu[0], m1 = mu[1];
    float v = x[xo + h];
    v += w[0] * m0.x + w[1] * m0.y + w[2] * m0.z + w[3] * m0.w +
         w[4] * m1.x + w[5] * m1.y + w[6] * m1.z + w[7] * m1.w;
    XE[eo + h] = f2bf(v);
  }
}

// Cg/Cu[f,t,kr] = bf16(Cat_qa * soft[t,f,kr>>3])
__global__ void k_cw(const float* __restrict__ Cat,
                     const float* __restrict__ soft, u16* __restrict__ Cg,
                     u16* __restrict__ Cu) {
  const long n = 8L * TT * 64;
  long i = (long)blockIdx.x * blockDim.x + threadIdx.x;
  long st = (long)gridDim.x * blockDim.x;
  for (; i < n; i += st) {
    int kr = (int)(i & 63);
    int t = (int)((i >> 6) & 1023);
    int f = (int)(i >> 16);
    float wv = soft[t * 64 + f * 8 + (kr >> 3)];
    const float* row = Cat + ((long)f * TT + t) * NCAT;
    Cg[i] = f2bf(row[1408 + kr] * wv);
    Cu[i] = f2bf(row[2880 + kr] * wv);
  }
}

__global__ __launch_bounds__(256) void k_h(const float* __restrict__ Cat,
                                           u16* __restrict__ Hb) {
  const int ft = blockIdx.x;  // f*1024+t
  const float* row = Cat + (long)ft * NCAT;
  u16* orow = Hb + (long)ft * II;
#pragma unroll
  for (int it = 0; it < 6; it++) {
    int ii = threadIdx.x + it * 256;
    if (ii < II) orow[ii] = f2bf(silu(row[ii]) * row[1472 + ii]);
  }
}

__global__ __launch_bounds__(256) void k_hsh(const float* __restrict__ Cat,
                                             u16* __restrict__ Hsh) {
  const int t = blockIdx.x;
  const float* g = Cat + (8L * TT + t) * NCAT;
  const float* u = Cat + (9L * TT + t) * NCAT;
#pragma unroll
  for (int it = 0; it < 11; it++) {
    int ii = threadIdx.x + it * 256;
    Hsh[(long)t * ISHc + ii] = f2bf(silu(g[ii]) * u[ii]);
  }
}

__global__ void k_cd(const float* __restrict__ Dcat,
                     const float* __restrict__ soft, u16* __restrict__ Cd) {
  const long n = 8L * TT * 64;
  long i = (long)blockIdx.x * blockDim.x + threadIdx.x;
  long st = (long)gridDim.x * blockDim.x;
  for (; i < n; i += st) {
    int kr = (int)(i & 63);
    int t = (int)((i >> 6) & 1023);
    int f = (int)(i >> 16);
    Cd[i] = f2bf(Dcat[((long)f * TT + t) * NDC + 2048 + kr] *
                 soft[t * 64 + f * 8 + (kr >> 3)]);
  }
}

// out[t,h] = Dcat[z=8][t,h] + sum_f scalar[t,f] * Dcat[f][t,h]
__global__ void k_final(const float* __restrict__ Dcat,
                        const float* __restrict__ scalar,
                        float* __restrict__ out) {
  const long n = (long)TT * HH;
  long i = (long)blockIdx.x * blockDim.x + threadIdx.x;
  long st = (long)gridDim.x * blockDim.x;
  for (; i < n; i += st) {
    int t = (int)(i >> 11), h = (int)(i & 2047);
    float a = Dcat[(8L * TT + t) * NDC + h];
#pragma unroll
    for (int f = 0; f < FF; f++)
      a += scalar[t * 8 + f] * Dcat[((long)f * TT + t) * NDC + h];
    out[i] = a;
  }
}

// ======================= launch =======================
extern "C" void kernel_launch(void* const* d_in, const int* in_sizes, int n_in,
                              void* d_out, int out_size, void* d_ws,
                              size_t ws_size, hipStream_t stream) {
  const float* xf   = (const float*)d_in[0];
  const float* gwf  = (const float*)d_in[1];
  const int*   invp = (const int*)d_in[2];
  const float* muWf = (const float*)d_in[3];
  const float* gW   = (const float*)d_in[4];
  const float* gqa  = (const float*)d_in[5];
  const float* gqb  = (const float*)d_in[6];
  const float* gscf = (const float*)d_in[7];
  const float* uW   = (const float*)d_in[8];
  const float* uqa  = (const float*)d_in[9];
  const float* uqb  = (const float*)d_in[10];
  const float* uscf = (const float*)d_in[11];
  const float* dW   = (const float*)d_in[12];
  const float* dqa  = (const float*)d_in[13];
  const float* dqb  = (const float*)d_in[14];
  const float* dscf = (const float*)d_in[15];
  const float* shgW = (const float*)d_in[16];
  const float* shuW = (const float*)d_in[17];
  const float* shdW = (const float*)d_in[18];
  float* outp = (float*)d_out;

  // ---- workspace layout with lifetime aliasing (peak ~274 MiB) ----
  constexpr long SZ_WCAT = 10L * NCAT * HH * 2;     // 120,586,240
  constexpr long SZ_WD   = 8L * NDC * II * 2;       //  47,579,136 (aliases Wcat)
  constexpr long SZ_SHD  = (long)HH * ISHc * 2;     //  11,534,336 (aliases Wcat)
  constexpr long SZ_QBI  = 8L * II * 64 * 2;
  constexpr long SZ_QBH  = 8L * HH * 64 * 2;
  constexpr long SZ_XB   = (long)TT * HH * 2;
  constexpr long SZ_SOFT = (long)TT * 64 * 4;
  constexpr long SZ_SCAL = (long)TT * 8 * 4;
  constexpr long SZ_XE   = 8L * TT * HH * 2;        //  33,554,432 (-> Hb+Hsh)
  constexpr long SZ_CAT  = 10L * TT * NCAT * 4;     // 120,586,240 (-> Dcat)
  constexpr long SZ_C    = 8L * TT * 64 * 2;

  char* base = (char*)d_ws;
  size_t off = 0;
  auto take = [&](long sz) { char* r = base + off; off += (size_t)sz; return r; };
  char* R1 = take(SZ_WCAT);
  u16* Wcat = (u16*)R1;
  u16* Wd   = (u16*)R1;                     // after G1, Wcat region is dead
  u16* SHd  = (u16*)(R1 + SZ_WD);
  u16* QBg = (u16*)take(SZ_QBI);
  u16* QBu = (u16*)take(SZ_QBI);
  u16* QBd = (u16*)take(SZ_QBH);
  u16* Xb  = (u16*)take(SZ_XB);
  float* Soft = (float*)take(SZ_SOFT);
  float* Scal = (float*)take(SZ_SCAL);
  char* RXe = take(SZ_XE);
  u16* Xe  = (u16*)RXe;
  u16* Hb  = (u16*)RXe;                     // after G1, Xe is dead
  u16* Hsh = (u16*)(RXe + 8L * TT * II * 2);
  char* RCat = take(SZ_CAT);
  float* Cat  = (float*)RCat;
  float* Dcat = (float*)RCat;               // after k_hsh, Cat is dead
  u16* Cg = (u16*)take(SZ_C);
  u16* Cu = (u16*)take(SZ_C);
  u16* Cd = (u16*)take(SZ_C);
  if (ws_size < off) return;  // loud failure rather than OOB corruption

  // 1) conversions needed before G1
  k_cvt_wcat<<<2048, 256, 0, stream>>>(gW, gqa, uW, uqa, shgW, shuW, Wcat);
  k_cvt_x<<<512, 256, 0, stream>>>(xf, Xb);
  k_qbt3<<<2048, 256, 0, stream>>>(gqb, uqb, dqb, QBg, QBu, QBd);

  // 2) gating + per-expert input
  k_gate<<<TT, 64, 0, stream>>>(xf, gwf, invp, Soft, Scal);
  k_xe<<<dim3(TT, FF), 256, 0, stream>>>(xf, muWf, Soft, Xe);

  // 3) mega-GEMM 1: expert gate/up (+qa) and shared gate/up -> Cat
  k_g1<<<1840, 256, 0, stream>>>(Xe, Xb, Wcat, Cat);

  // 4) down weights convert (into the now-dead Wcat region)
  k_cvt_wd<<<2048, 256, 0, stream>>>(dW, dqa, shdW, Wd, SHd);

  // 5) mix epilogues for gate/up, then activation
  k_cw<<<512, 256, 0, stream>>>(Cat, Soft, Cg, Cu);
  k_m1<<<1408, 256, 0, stream>>>(Cg, Cu, QBg, QBu, Cat, gscf, uscf);
  k_h<<<8192, 256, 0, stream>>>(Cat, Hb);
  k_hsh<<<1024, 256, 0, stream>>>(Cat, Hsh);

  // 6) mega-GEMM 2: expert down (+qa) and shared down -> Dcat (aliases Cat)
  k_g2<<<1224, 256, 0, stream>>>(Hb, Hsh, Wd, SHd, Dcat);

  // 7) down mix epilogue + weighted combine
  k_cd<<<512, 256, 0, stream>>>(Dcat, Soft, Cd);
  k_m2<<<1024, 256, 0, stream>>>(Cd, QBd, Dcat, dscf);
  k_final<<<1024, 256, 0, stream>>>(Dcat, Scal, outp);
}

// Round 3
// 898.766 us; speedup vs baseline: 1.2630x; 1.0190x over previous
//
#include <hip/hip_runtime.h>

typedef unsigned short u16;
typedef __attribute__((ext_vector_type(8))) short bf16x8;   // 8 bf16 in 4 VGPRs
typedef __attribute__((ext_vector_type(4))) float f32x4;

#define DEVI __device__ __forceinline__

// ---- problem constants ----
static constexpr int TT = 1024, HH = 2048, II = 1408, FF = 8, ISHc = 2816;
static constexpr int NCP = 3072;   // padded: 1408 gate |64 gqa |1408 up |64 uqa |128 pad
static constexpr int NDC = 2112;   // 2048 down | 64 down_qa

DEVI u16 f2bf(float f) {  // RNE float->bf16
  unsigned u = __float_as_uint(f);
  u += 0x7FFFu + ((u >> 16) & 1u);
  return (u16)(u >> 16);
}
DEVI float silu(float x) { return x / (1.f + __expf(-x)); }
DEVI void gload16(const void* g, void* lds) {
  __builtin_amdgcn_global_load_lds(
      (const __attribute__((address_space(1))) unsigned*)g,
      (__attribute__((address_space(3))) unsigned*)lds, 16, 0, 0);
}
// m204 bijective XCD-chunk swizzle (all grids are %8==0)
DEVI int xswz(int o, int nwg) { return (o & 7) * (nwg >> 3) + (o >> 3); }

// ============== mega GEMM: 256x256 tile, BK=32, 3-buffer counted-vmcnt ======
// C(256x256 tile) = A(row-major,ldA) x B^T (B rows n, stride Kd), fp32 C=acc.
// 512 thr = 8 waves (2Mx4N), wave tile 128x64. 2 phases/K-tile, 16 MFMA each.
// Pipeline ledger: stage tile t+2 (A-half in phase A, B-half in phase B) while
// computing t; vmcnt(4) at phase B => tile t+1 fully landed before its reads.
// Raw s_barrier (no vmcnt0 drain). Tail: redundant clamped staging keeps the
// vmcnt ledger uniform (stores into a dead buffer, never read).
DEVI void mega_core(const u16* __restrict__ A, int ldA,
                    const u16* __restrict__ B, int N, int Kd,
                    float* __restrict__ C, int ldC, int mB, int nB) {
  __shared__ u16 As[3][256 * 32];
  __shared__ u16 Bs[3][256 * 32];
  const int tid = threadIdx.x;
  const int l = tid & 63, w = tid >> 6;
  const int wm = w >> 2, wn = w & 3;
  const int lr = l & 15, lg = l >> 4;

  // staging: chunk c in [0,1024): row=c>>2, kchunk=c&3 (16B). thread: c=tid, c=512+tid
  const int r0 = tid >> 2, kc = tid & 3;
  const u16* aS0 = A + (long)(mB + r0) * ldA + kc * 8;
  const u16* aS1 = A + (long)(mB + 128 + r0) * ldA + kc * 8;
  int nr0 = nB + r0;        if (nr0 > N - 1) nr0 = N - 1;
  int nr1 = nB + 128 + r0;  if (nr1 > N - 1) nr1 = N - 1;
  const u16* bS0 = B + (long)nr0 * Kd + kc * 8;
  const u16* bS1 = B + (long)nr1 * Kd + kc * 8;
  u16* aD0 = &As[0][tid * 8];
  u16* aD1 = &As[0][(512 + tid) * 8];
  u16* bD0 = &Bs[0][tid * 8];
  u16* bD1 = &Bs[0][(512 + tid) * 8];
  const int BUF = 256 * 32;  // elems per buffer

  const int aRd = (wm * 128 + lr) * 32 + lg * 8;
  const int bRd = (wn * 64 + lr) * 32 + lg * 8;

  f32x4 acc[8][4];
#pragma unroll
  for (int m = 0; m < 8; m++)
#pragma unroll
    for (int n = 0; n < 4; n++) acc[m][n] = (f32x4){0.f, 0.f, 0.f, 0.f};

  const int NT = Kd >> 5;  // K-tiles of 32
  // prologue: stage tiles 0,1
  gload16(aS0, aD0);            gload16(aS1, aD1);
  gload16(bS0, bD0);            gload16(bS1, bD1);
  gload16(aS0 + 32, aD0 + BUF); gload16(aS1 + 32, aD1 + BUF);
  gload16(bS0 + 32, bD0 + BUF); gload16(bS1 + 32, bD1 + BUF);
  asm volatile("s_waitcnt vmcnt(4)" ::: "memory");  // tile 0 landed
  __builtin_amdgcn_s_barrier();
  __builtin_amdgcn_sched_barrier(0);

  int p = 0;
  for (int t = 0; t < NT; ++t) {
    const int pn = (p + 2 >= 3) ? p - 1 : p + 2;          // (t+2)%3
    const long ko = (long)((t + 2 < NT) ? t + 2 : NT - 1) << 5;
    const u16* ap = &As[0][0] + (long)p * BUF;
    const u16* bp = &Bs[0][0] + (long)p * BUF;
    // ---------- phase A: read A m0-3 + B n0-3; stage A-half of t+2 ----------
    bf16x8 a0 = *(const bf16x8*)&ap[aRd + 0 * 512];
    bf16x8 a1 = *(const bf16x8*)&ap[aRd + 1 * 512];
    bf16x8 a2 = *(const bf16x8*)&ap[aRd + 2 * 512];
    bf16x8 a3 = *(const bf16x8*)&ap[aRd + 3 * 512];
    bf16x8 b0 = *(const bf16x8*)&bp[bRd + 0 * 512];
    bf16x8 b1 = *(const bf16x8*)&bp[bRd + 1 * 512];
    bf16x8 b2 = *(const bf16x8*)&bp[bRd + 2 * 512];
    bf16x8 b3 = *(const bf16x8*)&bp[bRd + 3 * 512];
    gload16(aS0 + ko, aD0 + (long)pn * BUF);
    gload16(aS1 + ko, aD1 + (long)pn * BUF);
    __builtin_amdgcn_s_barrier();
    __builtin_amdgcn_sched_barrier(0);
    __builtin_amdgcn_s_setprio(1);
    acc[0][0] = __builtin_amdgcn_mfma_f32_16x16x32_bf16(a0, b0, acc[0][0], 0, 0, 0);
    acc[0][1] = __builtin_amdgcn_mfma_f32_16x16x32_bf16(a0, b1, acc[0][1], 0, 0, 0);
    acc[0][2] = __builtin_amdgcn_mfma_f32_16x16x32_bf16(a0, b2, acc[0][2], 0, 0, 0);
    acc[0][3] = __builtin_amdgcn_mfma_f32_16x16x32_bf16(a0, b3, acc[0][3], 0, 0, 0);
    acc[1][0] = __builtin_amdgcn_mfma_f32_16x16x32_bf16(a1, b0, acc[1][0], 0, 0, 0);
    acc[1][1] = __builtin_amdgcn_mfma_f32_16x16x32_bf16(a1, b1, acc[1][1], 0, 0, 0);
    acc[1][2] = __builtin_amdgcn_mfma_f32_16x16x32_bf16(a1, b2, acc[1][2], 0, 0, 0);
    acc[1][3] = __builtin_amdgcn_mfma_f32_16x16x32_bf16(a1, b3, acc[1][3], 0, 0, 0);
    acc[2][0] = __builtin_amdgcn_mfma_f32_16x16x32_bf16(a2, b0, acc[2][0], 0, 0, 0);
    acc[2][1] = __builtin_amdgcn_mfma_f32_16x16x32_bf16(a2, b1, acc[2][1], 0, 0, 0);
    acc[2][2] = __builtin_amdgcn_mfma_f32_16x16x32_bf16(a2, b2, acc[2][2], 0, 0, 0);
    acc[2][3] = __builtin_amdgcn_mfma_f32_16x16x32_bf16(a2, b3, acc[2][3], 0, 0, 0);
    acc[3][0] = __builtin_amdgcn_mfma_f32_16x16x32_bf16(a3, b0, acc[3][0], 0, 0, 0);
    acc[3][1] = __builtin_amdgcn_mfma_f32_16x16x32_bf16(a3, b1, acc[3][1], 0, 0, 0);
    acc[3][2] = __builtin_amdgcn_mfma_f32_16x16x32_bf16(a3, b2, acc[3][2], 0, 0, 0);
    acc[3][3] = __builtin_amdgcn_mfma_f32_16x16x32_bf16(a3, b3, acc[3][3], 0, 0, 0);
    __builtin_amdgcn_s_setprio(0);
    __builtin_amdgcn_s_barrier();
    __builtin_amdgcn_sched_barrier(0);
    // ---------- phase B: read A m4-7; stage B-half of t+2; vmcnt(4) ----------
    bf16x8 a4 = *(const bf16x8*)&ap[aRd + 4 * 512];
    bf16x8 a5 = *(const bf16x8*)&ap[aRd + 5 * 512];
    bf16x8 a6 = *(const bf16x8*)&ap[aRd + 6 * 512];
    bf16x8 a7 = *(const bf16x8*)&ap[aRd + 7 * 512];
    gload16(bS0 + ko, bD0 + (long)pn * BUF);
    gload16(bS1 + ko, bD1 + (long)pn * BUF);
    asm volatile("s_waitcnt vmcnt(4)" ::: "memory");  // tile t+1 landed
    __builtin_amdgcn_s_barrier();
    __builtin_amdgcn_sched_barrier(0);
    __builtin_amdgcn_s_setprio(1);
    acc[4][0] = __builtin_amdgcn_mfma_f32_16x16x32_bf16(a4, b0, acc[4][0], 0, 0, 0);
    acc[4][1] = __builtin_amdgcn_mfma_f32_16x16x32_bf16(a4, b1, acc[4][1], 0, 0, 0);
    acc[4][2] = __builtin_amdgcn_mfma_f32_16x16x32_bf16(a4, b2, acc[4][2], 0, 0, 0);
    acc[4][3] = __builtin_amdgcn_mfma_f32_16x16x32_bf16(a4, b3, acc[4][3], 0, 0, 0);
    acc[5][0] = __builtin_amdgcn_mfma_f32_16x16x32_bf16(a5, b0, acc[5][0], 0, 0, 0);
    acc[5][1] = __builtin_amdgcn_mfma_f32_16x16x32_bf16(a5, b1, acc[5][1], 0, 0, 0);
    acc[5][2] = __builtin_amdgcn_mfma_f32_16x16x32_bf16(a5, b2, acc[5][2], 0, 0, 0);
    acc[5][3] = __builtin_amdgcn_mfma_f32_16x16x32_bf16(a5, b3, acc[5][3], 0, 0, 0);
    acc[6][0] = __builtin_amdgcn_mfma_f32_16x16x32_bf16(a6, b0, acc[6][0], 0, 0, 0);
    acc[6][1] = __builtin_amdgcn_mfma_f32_16x16x32_bf16(a6, b1, acc[6][1], 0, 0, 0);
    acc[6][2] = __builtin_amdgcn_mfma_f32_16x16x32_bf16(a6, b2, acc[6][2], 0, 0, 0);
    acc[6][3] = __builtin_amdgcn_mfma_f32_16x16x32_bf16(a6, b3, acc[6][3], 0, 0, 0);
    acc[7][0] = __builtin_amdgcn_mfma_f32_16x16x32_bf16(a7, b0, acc[7][0], 0, 0, 0);
    acc[7][1] = __builtin_amdgcn_mfma_f32_16x16x32_bf16(a7, b1, acc[7][1], 0, 0, 0);
    acc[7][2] = __builtin_amdgcn_mfma_f32_16x16x32_bf16(a7, b2, acc[7][2], 0, 0, 0);
    acc[7][3] = __builtin_amdgcn_mfma_f32_16x16x32_bf16(a7, b3, acc[7][3], 0, 0, 0);
    __builtin_amdgcn_s_setprio(0);
    __builtin_amdgcn_s_barrier();
    __builtin_amdgcn_sched_barrier(0);
    p = (p + 1 == 3) ? 0 : p + 1;
  }

  // C/D layout (m89-verified): col = lane&15, row = (lane>>4)*4 + reg
  const int colB = nB + wn * 64 + lr;
  const int rowB = mB + wm * 128 + lg * 4;
#pragma unroll
  for (int m = 0; m < 8; m++)
#pragma unroll
    for (int n = 0; n < 4; n++) {
      const int col = colB + n * 16;
      if (col < N) {
        f32x4 v = acc[m][n];
        float* pc = C + (long)(rowB + m * 16) * ldC + col;
#pragma unroll
        for (int j = 0; j < 4; j++) pc[(long)j * ldC] = v[j];
      }
    }
}

// G1: 480 blocks: z=0..7 expert gate|qa|up|qa (A=Xe[f]); z=8,9 shared (A=Xb).
__global__ __launch_bounds__(512, 2) void k_g1(const u16* __restrict__ Xe,
                                               const u16* __restrict__ Xb,
                                               const u16* __restrict__ Wcat,
                                               float* __restrict__ Cat) {
  int wg = xswz(blockIdx.x, 480);
  int z = wg / 48, rr = wg % 48;
  int mB = (rr / 12) * 256, nB = (rr % 12) * 256;
  const u16* A = (z < 8) ? Xe + (long)z * TT * HH : Xb;
  mega_core(A, HH, Wcat + (long)z * NCP * HH, NCP, HH,
            Cat + (long)z * TT * NCP, NCP, mB, nB);
}

// G2: 320 blocks. Per-XCD chunk (40) = 4 shared-down tiles (K=2816) + one
// expert's 36 tiles (K=1408) -> uniform 44 work-units per XCD.
__global__ __launch_bounds__(512, 2) void k_g2(const u16* __restrict__ Hb,
                                               const u16* __restrict__ Hsh,
                                               const u16* __restrict__ Wd,
                                               const u16* __restrict__ SHd,
                                               float* __restrict__ Dcat) {
  int wg = xswz(blockIdx.x, 320);
  int x = wg / 40, j = wg % 40;
  if (j < 4) {
    int s = x * 4 + j;
    int mB = (s / 8) * 256, nB = (s % 8) * 256;
    mega_core(Hsh, ISHc, SHd, HH, ISHc, Dcat + 8L * TT * NDC, NDC, mB, nB);
  } else {
    int e = j - 4, f = x;
    int mB = (e / 9) * 256, nB = (e % 9) * 256;
    mega_core(Hb + (long)f * TT * II, II, Wd + (long)f * NDC * II, NDC, II,
              Dcat + (long)f * TT * NDC, NDC, mB, nB);
  }
}

// ============== mix GEMM (128x128, BK=32, K=64): C += scale[col]*acc ========
DEVI void mix_core(const u16* __restrict__ A, const u16* __restrict__ B,
                   float* __restrict__ C, const float* __restrict__ scale,
                   int N, int Kd, int ldC, int mBase, int nBase) {
  __shared__ u16 As[128 * 32];
  __shared__ u16 Bs[128 * 32];
  const int tid = threadIdx.x;
  const int c0 = tid, c1 = tid + 256;
  const int kc0 = (c0 & 3) * 8, kc1 = (c1 & 3) * 8;
  const u16* aS0 = A + (long)(mBase + (c0 >> 2)) * Kd + kc0;
  const u16* aS1 = A + (long)(mBase + (c1 >> 2)) * Kd + kc1;
  int nr0 = nBase + (c0 >> 2); if (nr0 > N - 1) nr0 = N - 1;
  int nr1 = nBase + (c1 >> 2); if (nr1 > N - 1) nr1 = N - 1;
  const u16* bS0 = B + (long)nr0 * Kd + kc0;
  const u16* bS1 = B + (long)nr1 * Kd + kc1;

  const int l = tid & 63, w = tid >> 6;
  const int wr = (w >> 1) * 64, wc = (w & 1) * 64;
  const int lr = l & 15, lk = (l >> 4) * 8;

  f32x4 acc[4][4];
#pragma unroll
  for (int m = 0; m < 4; m++)
#pragma unroll
    for (int n = 0; n < 4; n++) acc[m][n] = (f32x4){0.f, 0.f, 0.f, 0.f};

  for (int k0 = 0; k0 < Kd; k0 += 32) {
    __syncthreads();
    gload16(aS0 + k0, &As[c0 * 8]);
    gload16(aS1 + k0, &As[c1 * 8]);
    gload16(bS0 + k0, &Bs[c0 * 8]);
    gload16(bS1 + k0, &Bs[c1 * 8]);
    __syncthreads();
    bf16x8 av[4], bv[4];
#pragma unroll
    for (int m = 0; m < 4; m++)
      av[m] = *(const bf16x8*)&As[(wr + m * 16 + lr) * 32 + lk];
#pragma unroll
    for (int n = 0; n < 4; n++)
      bv[n] = *(const bf16x8*)&Bs[(wc + n * 16 + lr) * 32 + lk];
#pragma unroll
    for (int m = 0; m < 4; m++)
#pragma unroll
      for (int n = 0; n < 4; n++)
        acc[m][n] = __builtin_amdgcn_mfma_f32_16x16x32_bf16(av[m], bv[n],
                                                            acc[m][n], 0, 0, 0);
  }

  const int colB = nBase + wc + lr;
  const int rowB = mBase + wr + (l >> 4) * 4;
#pragma unroll
  for (int m = 0; m < 4; m++)
#pragma unroll
    for (int n = 0; n < 4; n++) {
      const int col = colB + n * 16;
      if (col < N) {
        const float sc = scale[col];
        f32x4 v = acc[m][n];
        float* pc = C + (long)(rowB + m * 16) * ldC + col;
#pragma unroll
        for (int j = 0; j < 4; j++) pc[(long)j * ldC] += sc * v[j];
      }
    }
}

// M1: gate-mix (z<8) / up-mix (z>=8) into Cat. 1408 blocks.
__global__ __launch_bounds__(256) void k_m1(const u16* __restrict__ Cg,
                                            const u16* __restrict__ Cu,
                                            const u16* __restrict__ QBg,
                                            const u16* __restrict__ QBu,
                                            float* __restrict__ Cat,
                                            const float* __restrict__ gsc,
                                            const float* __restrict__ usc) {
  int wg = xswz(blockIdx.x, 1408);
  int z = wg / 88, rr = wg % 88;
  int nB = (rr % 11) * 128, mB = (rr / 11) * 128;
  int f = z & 7;
  bool gate = z < 8;
  const u16* A = (gate ? Cg : Cu) + (long)f * TT * 64;
  const u16* B = (gate ? QBg : QBu) + (long)f * II * 64;
  float* C = Cat + (long)f * TT * NCP + (gate ? 0 : 1472);
  const float* sc = (gate ? gsc : usc) + (long)f * II;
  mix_core(A, B, C, sc, II, 64, NCP, mB, nB);
}

// M2: down-mix into Dcat. 1024 blocks.
__global__ __launch_bounds__(256) void k_m2(const u16* __restrict__ Cd,
                                            const u16* __restrict__ QBd,
                                            float* __restrict__ Dcat,
                                            const float* __restrict__ dsc) {
  int wg = xswz(blockIdx.x, 1024);
  int f = wg / 128, rr = wg % 128;
  int nB = (rr % 16) * 128, mB = (rr / 16) * 128;
  mix_core(Cd + (long)f * TT * 64, QBd + (long)f * HH * 64,
           Dcat + (long)f * TT * NDC, dsc + (long)f * HH, HH, 64, NDC, mB, nB);
}

// ======================= gating (fp32, exact top-k semantics) ================
__global__ __launch_bounds__(64) void k_gate(const float* __restrict__ x,
                                             const float* __restrict__ gw,
                                             const int* __restrict__ inv,
                                             float* __restrict__ soft,
                                             float* __restrict__ scalar) {
  const int t = blockIdx.x;
  const int e = threadIdx.x;
  __shared__ float4 xs[512];
  const float4* xr = (const float4*)(x + (long)t * HH);
#pragma unroll
  for (int i = 0; i < 8; i++) xs[e + i * 64] = xr[e + i * 64];
  __syncthreads();
  const float4* g = (const float4*)(gw + (long)e * HH);
  float s = 0.f;
#pragma unroll 4
  for (int i = 0; i < 512; i++) {
    float4 gv = g[i];
    float4 xv = xs[i];
    s += gv.x * xv.x + gv.y * xv.y + gv.z * xv.z + gv.w * xv.w;
  }
  float mx = s;
#pragma unroll
  for (int d = 1; d < 64; d <<= 1) mx = fmaxf(mx, __shfl_xor(mx, d));
  float pe = __expf(s - mx);
  float sm = pe;
#pragma unroll
  for (int d = 1; d < 64; d <<= 1) sm += __shfl_xor(sm, d);
  float prob = pe / sm;
  float wd = 0.f;
  bool sel = false;
  for (int it = 0; it < 6; it++) {
    float cand = sel ? -1.f : prob;
    float cmx = cand;
#pragma unroll
    for (int d = 1; d < 64; d <<= 1) cmx = fmaxf(cmx, __shfl_xor(cmx, d));
    unsigned long long b = __ballot(cand == cmx);
    int win = __ffsll((long long)b) - 1;
    if (e == win) { sel = true; wd = prob; }
  }
  int src = inv[e];
  float flat = __shfl(wd, src);
  float sum8 = flat;
#pragma unroll
  for (int d = 1; d < 8; d <<= 1) sum8 += __shfl_xor(sum8, d);
  float masked = (flat == 0.f) ? -1e9f : flat;
  float m8 = masked;
#pragma unroll
  for (int d = 1; d < 8; d <<= 1) m8 = fmaxf(m8, __shfl_xor(m8, d));
  float p = __expf(masked - m8);
  float ps = p;
#pragma unroll
  for (int d = 1; d < 8; d <<= 1) ps += __shfl_xor(ps, d);
  soft[(long)t * 64 + e] = p / ps;
  if ((e & 7) == 0) scalar[(long)t * 8 + (e >> 3)] = sum8;
}

// ======================= conversion / glue kernels ===========================
// Wcat: 10 x (3072 x 2048) bf16; z<8: [gW|gqa|uW|uqa|pad0]; z=8/9: sh +/pad0.
__global__ void k_cvt_wcat(const float* __restrict__ gW,
                           const float* __restrict__ gqa,
                           const float* __restrict__ uW,
                           const float* __restrict__ uqa,
                           const float* __restrict__ shg,
                           const float* __restrict__ shu,
                           u16* __restrict__ Wcat) {
  const long tot = 10L * NCP * (HH / 4);
  long i = (long)blockIdx.x * blockDim.x + threadIdx.x;
  long st = (long)gridDim.x * blockDim.x;
  for (; i < tot; i += st) {
    int h4 = (int)(i & 511);
    long rz = i >> 9;
    int row = (int)(rz % NCP);
    int z = (int)(rz / NCP);
    const float* src = nullptr;
    if (z < 8) {
      if (row < 1408)       src = gW  + ((long)z * II + row) * HH;
      else if (row < 1472)  src = gqa + ((long)z * 64 + row - 1408) * HH;
      else if (row < 2880)  src = uW  + ((long)z * II + row - 1472) * HH;
      else if (row < 2944)  src = uqa + ((long)z * 64 + row - 2880) * HH;
    } else if (row < ISHc) {
      src = ((z == 8) ? shg : shu) + (long)row * HH;
    }
    ushort4 o;
    if (src) {
      float4 v = ((const float4*)src)[h4];
      o.x = f2bf(v.x); o.y = f2bf(v.y); o.z = f2bf(v.z); o.w = f2bf(v.w);
    } else { o.x = 0; o.y = 0; o.z = 0; o.w = 0; }
    ((ushort4*)Wcat)[i] = o;
  }
}

// Wd (8 x 2112 x 1408) = [dW|dqa](f);  SHd (2048 x 2816) = sh_down.
__global__ void k_cvt_wd(const float* __restrict__ dW,
                         const float* __restrict__ dqa,
                         const float* __restrict__ shdW, u16* __restrict__ Wd,
                         u16* __restrict__ SHd) {
  const long s1 = 8L * NDC * (II / 4);
  const long s2 = s1 + (long)HH * (ISHc / 4);
  long i = (long)blockIdx.x * blockDim.x + threadIdx.x;
  long st = (long)gridDim.x * blockDim.x;
  for (; i < s2; i += st) {
    ushort4 o;
    if (i < s1) {
      int k4 = (int)(i % 352);
      long rz = i / 352;
      int row = (int)(rz % NDC);
      int f = (int)(rz / NDC);
      const float* src = (row < HH) ? dW + ((long)f * HH + row) * II
                                    : dqa + ((long)f * 64 + (row - HH)) * II;
      float4 v = ((const float4*)src)[k4];
      o.x = f2bf(v.x); o.y = f2bf(v.y); o.z = f2bf(v.z); o.w = f2bf(v.w);
      ((ushort4*)Wd)[i] = o;
    } else {
      long j = i - s1;
      float4 v = ((const float4*)shdW)[j];
      o.x = f2bf(v.x); o.y = f2bf(v.y); o.z = f2bf(v.z); o.w = f2bf(v.w);
      ((ushort4*)SHd)[j] = o;
    }
  }
}

__global__ void k_cvt_x(const float* __restrict__ x, u16* __restrict__ Xb) {
  const long n4 = (long)TT * HH / 4;
  long i = (long)blockIdx.x * blockDim.x + threadIdx.x;
  long st = (long)gridDim.x * blockDim.x;
  for (; i < n4; i += st) {
    float4 v = ((const float4*)x)[i];
    ushort4 o;
    o.x = f2bf(v.x); o.y = f2bf(v.y); o.z = f2bf(v.z); o.w = f2bf(v.w);
    ((ushort4*)Xb)[i] = o;
  }
}

// QB[f,i,kr] = qb[f, kr>>3, i, kr&7]
__global__ void k_qbt3(const float* __restrict__ gqb,
                       const float* __restrict__ uqb,
                       const float* __restrict__ dqb, u16* __restrict__ QBg,
                       u16* __restrict__ QBu, u16* __restrict__ QBd) {
  const long n1 = 8L * II * 64, n2 = 2 * n1, n3 = n2 + 8L * HH * 64;
  long i = (long)blockIdx.x * blockDim.x + threadIdx.x;
  long st = (long)gridDim.x * blockDim.x;
  for (; i < n3; i += st) {
    const float* q; u16* d; int N; long j;
    if (i < n1)      { q = gqb; d = QBg; N = II; j = i; }
    else if (i < n2) { q = uqb; d = QBu; N = II; j = i - n1; }
    else             { q = dqb; d = QBd; N = HH; j = i - n2; }
    int kr = (int)(j & 63);
    long rest = j >> 6;
    int ii = (int)(rest % N);
    int f = (int)(rest / N);
    d[j] = f2bf(q[(((long)(f * 8 + (kr >> 3)) * N + ii) << 3) + (kr & 7)]);
  }
}

// XE[f,t,h] = x[t,h] + sum_k soft[t,f,k]*muW[f,h,k]
__global__ void k_xe(const float* __restrict__ x, const float* __restrict__ muW,
                     const float* __restrict__ soft, u16* __restrict__ XE) {
  const int t = blockIdx.x, f = blockIdx.y, tid = threadIdx.x;
  float w[8];
#pragma unroll
  for (int k = 0; k < 8; k++) w[k] = soft[(long)t * 64 + f * 8 + k];
  const long xo = (long)t * HH;
  const long eo = ((long)f * TT + t) * HH;
#pragma unroll
  for (int i = 0; i < 8; i++) {
    int h = tid + i * 256;
    const float4* mu = (const float4*)(muW + ((long)f * HH + h) * 8);
    float4 m0 = mu[0], m1 = mu[1];
    float v = x[xo + h];
    v += w[0] * m0.x + w[1] * m0.y + w[2] * m0.z + w[3] * m0.w +
         w[4] * m1.x + w[5] * m1.y + w[6] * m1.z + w[7] * m1.w;
    XE[eo + h] = f2bf(v);
  }
}

// Cg/Cu[f,t,kr] = bf16(Cat_qa * soft[t,f,kr>>3])
__global__ void k_cw(const float* __restrict__ Cat,
                     const float* __restrict__ soft, u16* __restrict__ Cg,
                     u16* __restrict__ Cu) {
  const long n = 8L * TT * 64;
  long i = (long)blockIdx.x * blockDim.x + threadIdx.x;
  long st = (long)gridDim.x * blockDim.x;
  for (; i < n; i += st) {
    int kr = (int)(i & 63);
    int t = (int)((i >> 6) & 1023);
    int f = (int)(i >> 16);
    float wv = soft[t * 64 + f * 8 + (kr >> 3)];
    const float* row = Cat + ((long)f * TT + t) * NCP;
    Cg[i] = f2bf(row[1408 + kr] * wv);
    Cu[i] = f2bf(row[2880 + kr] * wv);
  }
}

__global__ __launch_bounds__(256) void k_h(const float* __restrict__ Cat,
                                           u16* __restrict__ Hb) {
  const int ft = blockIdx.x;  // f*1024+t
  const float* row = Cat + (long)ft * NCP;
  u16* orow = Hb + (long)ft * II;
#pragma unroll
  for (int it = 0; it < 6; it++) {
    int ii = threadIdx.x + it * 256;
    if (ii < II) orow[ii] = f2bf(silu(row[ii]) * row[1472 + ii]);
  }
}

__global__ __launch_bounds__(256) void k_hsh(const float* __restrict__ Cat,
                                             u16* __restrict__ Hsh) {
  const int t = blockIdx.x;
  const float* g = Cat + (8L * TT + t) * NCP;
  const float* u = Cat + (9L * TT + t) * NCP;
#pragma unroll
  for (int it = 0; it < 11; it++) {
    int ii = threadIdx.x + it * 256;
    Hsh[(long)t * ISHc + ii] = f2bf(silu(g[ii]) * u[ii]);
  }
}

__global__ void k_cd(const float* __restrict__ Dcat,
                     const float* __restrict__ soft, u16* __restrict__ Cd) {
  const long n = 8L * TT * 64;
  long i = (long)blockIdx.x * blockDim.x + threadIdx.x;
  long st = (long)gridDim.x * blockDim.x;
  for (; i < n; i += st) {
    int kr = (int)(i & 63);
    int t = (int)((i >> 6) & 1023);
    int f = (int)(i >> 16);
    Cd[i] = f2bf(Dcat[((long)f * TT + t) * NDC + 2048 + kr] *
                 soft[t * 64 + f * 8 + (kr >> 3)]);
  }
}

__global__ void k_final(const float* __restrict__ Dcat,
                        const float* __restrict__ scalar,
                        float* __restrict__ out) {
  const long n = (long)TT * HH;
  long i = (long)blockIdx.x * blockDim.x + threadIdx.x;
  long st = (long)gridDim.x * blockDim.x;
  for (; i < n; i += st) {
    int t = (int)(i >> 11), h = (int)(i & 2047);
    float a = Dcat[(8L * TT + t) * NDC + h];
#pragma unroll
    for (int f = 0; f < FF; f++)
      a += scalar[t * 8 + f] * Dcat[((long)f * TT + t) * NDC + h];
    out[i] = a;
  }
}

// ======================= launch =======================
extern "C" void kernel_launch(void* const* d_in, const int* in_sizes, int n_in,
                              void* d_out, int out_size, void* d_ws,
                              size_t ws_size, hipStream_t stream) {
  const float* xf   = (const float*)d_in[0];
  const float* gwf  = (const float*)d_in[1];
  const int*   invp = (const int*)d_in[2];
  const float* muWf = (const float*)d_in[3];
  const float* gW   = (const float*)d_in[4];
  const float* gqa  = (const float*)d_in[5];
  const float* gqb  = (const float*)d_in[6];
  const float* gscf = (const float*)d_in[7];
  const float* uW   = (const float*)d_in[8];
  const float* uqa  = (const float*)d_in[9];
  const float* uqb  = (const float*)d_in[10];
  const float* uscf = (const float*)d_in[11];
  const float* dW   = (const float*)d_in[12];
  const float* dqa  = (const float*)d_in[13];
  const float* dqb  = (const float*)d_in[14];
  const float* dscf = (const float*)d_in[15];
  const float* shgW = (const float*)d_in[16];
  const float* shuW = (const float*)d_in[17];
  const float* shdW = (const float*)d_in[18];
  float* outp = (float*)d_out;

  constexpr long SZ_WCAT = 10L * NCP * HH * 2;     // 125,829,120
  constexpr long SZ_WD   = 8L * NDC * II * 2;      // aliases WCAT after G1
  constexpr long SZ_QBI  = 8L * II * 64 * 2;
  constexpr long SZ_QBH  = 8L * HH * 64 * 2;
  constexpr long SZ_XB   = (long)TT * HH * 2;
  constexpr long SZ_SOFT = (long)TT * 64 * 4;
  constexpr long SZ_SCAL = (long)TT * 8 * 4;
  constexpr long SZ_XE   = 8L * TT * HH * 2;       // -> Hb + Hsh after G1
  constexpr long SZ_CAT  = 10L * TT * NCP * 4;     // -> Dcat after k_hsh
  constexpr long SZ_C    = 8L * TT * 64 * 2;

  char* base = (char*)d_ws;
  size_t off = 0;
  auto take = [&](long sz) { char* r = base + off; off += (size_t)sz; return r; };
  char* R1 = take(SZ_WCAT);
  u16* Wcat = (u16*)R1;
  u16* Wd   = (u16*)R1;
  u16* SHd  = (u16*)(R1 + SZ_WD);
  u16* QBg = (u16*)take(SZ_QBI);
  u16* QBu = (u16*)take(SZ_QBI);
  u16* QBd = (u16*)take(SZ_QBH);
  u16* Xb  = (u16*)take(SZ_XB);
  float* Soft = (float*)take(SZ_SOFT);
  float* Scal = (float*)take(SZ_SCAL);
  char* RXe = take(SZ_XE);
  u16* Xe  = (u16*)RXe;
  u16* Hb  = (u16*)RXe;
  u16* Hsh = (u16*)(RXe + 8L * TT * II * 2);
  char* RCat = take(SZ_CAT);
  float* Cat  = (float*)RCat;
  float* Dcat = (float*)RCat;
  u16* Cg = (u16*)take(SZ_C);
  u16* Cu = (u16*)take(SZ_C);
  u16* Cd = (u16*)take(SZ_C);
  if (ws_size < off) return;

  // 1) conversions for G1
  k_cvt_wcat<<<2048, 256, 0, stream>>>(gW, gqa, uW, uqa, shgW, shuW, Wcat);
  k_cvt_x<<<512, 256, 0, stream>>>(xf, Xb);
  k_qbt3<<<2048, 256, 0, stream>>>(gqb, uqb, dqb, QBg, QBu, QBd);

  // 2) gating + per-expert input
  k_gate<<<TT, 64, 0, stream>>>(xf, gwf, invp, Soft, Scal);
  k_xe<<<dim3(TT, FF), 256, 0, stream>>>(xf, muWf, Soft, Xe);

  // 3) mega-GEMM 1 (256^2 pipelined)
  k_g1<<<480, 512, 0, stream>>>(Xe, Xb, Wcat, Cat);

  // 4) down weights (into dead Wcat region)
  k_cvt_wd<<<2048, 256, 0, stream>>>(dW, dqa, shdW, Wd, SHd);

  // 5) mix epilogues + activation
  k_cw<<<512, 256, 0, stream>>>(Cat, Soft, Cg, Cu);
  k_m1<<<1408, 256, 0, stream>>>(Cg, Cu, QBg, QBu, Cat, gscf, uscf);
  k_h<<<8192, 256, 0, stream>>>(Cat, Hb);
  k_hsh<<<1024, 256, 0, stream>>>(Cat, Hsh);

  // 6) mega-GEMM 2 (256^2 pipelined)
  k_g2<<<320, 512, 0, stream>>>(Hb, Hsh, Wd, SHd, Dcat);

  // 7) down mix + combine
  k_cd<<<512, 256, 0, stream>>>(Dcat, Soft, Cd);
  k_m2<<<1024, 256, 0, stream>>>(Cd, QBd, Dcat, dscf);
  k_final<<<1024, 256, 0, stream>>>(Dcat, Scal, outp);
}